// Round 1
// baseline (107.165 us; speedup 1.0000x reference)
//
#include <hip/hip_runtime.h>

#define B_  4
#define C_  16
#define H_  64
#define W_  64
#define F_  32
#define R_  16            // rows per spatial tile
#define NT_ (H_ / R_)     // 4 tiles
#define CST 12            // LDS floats per (c,tap) coeff entry (10 used + 2 pad -> 48B stride, 16B aligned)

__global__ __launch_bounds__(256)
void ka_rconv_kernel(const float* __restrict__ xin,
                     const float* __restrict__ nums,
                     const float* __restrict__ denoms,
                     float* __restrict__ out) {
    // coeffs for this block's f: [c*9+tap][n0..n5,d0..d3,pad,pad]
    __shared__ alignas(16) float sc[C_ * 9 * CST];   // 1728 floats = 6.75 KB
    __shared__ float sx[(R_ + 2) * 66];              // padded x tile, 1188 floats = 4.64 KB

    const int tid = threadIdx.x;
    int bid = blockIdx.x;
    const int f    = bid % F_;  bid /= F_;
    const int tile = bid % NT_;
    const int b    = bid / NT_;
    const int row0 = tile * R_;

    // ---- stage coefficients for this f (coalesced global reads, once per block) ----
    {
        const float* np = nums + f * (C_ * 9 * 6);
        for (int i = tid; i < C_ * 9 * 6; i += 256) {
            int e = i / 6, j = i - e * 6;
            sc[e * CST + j] = np[i];
        }
        const float* dp = denoms + f * (C_ * 9 * 4);
        for (int i = tid; i < C_ * 9 * 4; i += 256) {
            int e = i / 4, j = i - e * 4;
            sc[e * CST + 6 + j] = dp[i];
        }
    }

    const int w  = tid & 63;   // column (wave-contiguous -> coalesced / conflict-free)
    const int rq = tid >> 6;   // row quadrant 0..3

    float acc[4] = {0.f, 0.f, 0.f, 0.f};

    for (int c = 0; c < C_; ++c) {
        __syncthreads();  // protect sx from previous iter; also covers sc staging on c==0
        // ---- stage zero-padded x tile for channel c ----
        const float* xc = xin + ((b * C_ + c) * H_) * W_;
        for (int i = tid; i < (R_ + 2) * 66; i += 256) {
            int ry = i / 66;
            int rx = i - ry * 66;
            int gy = row0 + ry - 1;
            int gx = rx - 1;
            float v = 0.f;
            if (gy >= 0 && gy < H_ && gx >= 0 && gx < W_)
                v = xc[gy * W_ + gx];
            sx[i] = v;
        }
        __syncthreads();

        const float* se = sc + c * 9 * CST;
        #pragma unroll
        for (int a = 0; a < 3; ++a) {
            #pragma unroll
            for (int bb = 0; bb < 3; ++bb) {
                const float* e = se + (a * 3 + bb) * CST;
                const float4 c0 = *(const float4*)(e);      // n0 n1 n2 n3
                const float4 c1 = *(const float4*)(e + 4);  // n4 n5 d0 d1
                const float2 c2 = *(const float2*)(e + 8);  // d2 d3
                #pragma unroll
                for (int p = 0; p < 4; ++p) {
                    const int r = rq * 4 + p;
                    const float xv = sx[(r + a) * 66 + (w + bb)];
                    // P = n0 + n1 x + ... + n5 x^5 (Horner)
                    float P = fmaf(c1.y, xv, c1.x);   // n5*x + n4
                    P = fmaf(P, xv, c0.w);
                    P = fmaf(P, xv, c0.z);
                    P = fmaf(P, xv, c0.y);
                    P = fmaf(P, xv, c0.x);
                    // Qs = d0 x + d1 x^2 + d2 x^3 + d3 x^4 = x*(((d3 x + d2) x + d1) x + d0)
                    float Q = fmaf(c2.y, xv, c2.x);   // d3*x + d2
                    Q = fmaf(Q, xv, c1.w);
                    Q = fmaf(Q, xv, c1.z);
                    Q *= xv;
                    Q = 1.0f + fabsf(Q);
                    acc[p] += P * __builtin_amdgcn_rcpf(Q);
                }
            }
        }
    }

    float* op = out + ((b * F_ + f) * H_ + row0) * W_ + w;
    #pragma unroll
    for (int p = 0; p < 4; ++p)
        op[(rq * 4 + p) * W_] = acc[p];
}

extern "C" void kernel_launch(void* const* d_in, const int* in_sizes, int n_in,
                              void* d_out, int out_size, void* d_ws, size_t ws_size,
                              hipStream_t stream) {
    const float* x      = (const float*)d_in[0];
    const float* nums   = (const float*)d_in[1];
    const float* denoms = (const float*)d_in[2];
    float* outp = (float*)d_out;
    dim3 grid(B_ * NT_ * F_);   // 512 blocks: (b, tile, f)
    ka_rconv_kernel<<<grid, 256, 0, stream>>>(x, nums, denoms, outp);
}

// Round 2
// 93.494 us; speedup vs baseline: 1.1462x; 1.1462x over previous
//
#include <hip/hip_runtime.h>

#define B_ 4
#define C_ 16
#define H_ 64
#define W_ 64
#define F_ 32
#define R_ 16
#define NT_ (H_ / R_)

__global__ __launch_bounds__(256)
void ka_rconv_kernel(const float* __restrict__ xin,
                     const float* __restrict__ nums,
                     const float* __restrict__ denoms,
                     float* __restrict__ out) {
    const int tid = threadIdx.x;
    int bid = blockIdx.x;
    const int f    = bid & (F_ - 1);  bid >>= 5;     // F_=32
    const int tile = bid & (NT_ - 1);                // NT_=4
    const int b    = bid >> 2;
    const int row0 = tile * R_;

    const int g   = tid & 15;        // column group (lane-contiguous -> coalesced)
    const int r   = tid >> 4;        // row within tile
    const int w0  = g * 4;           // this thread's 4 pixels: cols w0..w0+3
    const int gy0 = row0 + r;        // center row

    float acc[4] = {0.f, 0.f, 0.f, 0.f};

    const float* nbase = nums   + f * (C_ * 54);   // uniform -> scalar loads
    const float* dbase = denoms + f * (C_ * 36);
    const float* xb    = xin + (size_t)b * C_ * H_ * W_ + w0;

    #pragma unroll 2
    for (int c = 0; c < C_; ++c) {
        const float* xc = xb + c * (H_ * W_);
        // 3 rows x 6 cols of x into registers: row[a][0] = x[gy][w0-1] ... row[a][5] = x[gy][w0+4]
        float row[3][6];
        #pragma unroll
        for (int a = 0; a < 3; ++a) {
            const int gy   = gy0 + a - 1;
            const bool rok = (gy >= 0) && (gy < H_);
            const float* rp = xc + gy * W_;
            float4 m = rok ? *(const float4*)rp : make_float4(0.f, 0.f, 0.f, 0.f);
            float lo = (rok && (w0 > 0))       ? rp[-1] : 0.f;
            float hi = (rok && (w0 + 4 < W_))  ? rp[4]  : 0.f;
            row[a][0] = lo;  row[a][1] = m.x; row[a][2] = m.y;
            row[a][3] = m.z; row[a][4] = m.w; row[a][5] = hi;
        }

        const float* np = nbase + c * 54;
        const float* dp = dbase + c * 36;
        #pragma unroll
        for (int a = 0; a < 3; ++a) {
            #pragma unroll
            for (int bb = 0; bb < 3; ++bb) {
                const int t = a * 3 + bb;
                const float n0 = np[t*6+0], n1 = np[t*6+1], n2 = np[t*6+2];
                const float n3 = np[t*6+3], n4 = np[t*6+4], n5 = np[t*6+5];
                const float d0 = dp[t*4+0], d1 = dp[t*4+1], d2 = dp[t*4+2], d3 = dp[t*4+3];
                #pragma unroll
                for (int p = 0; p < 4; ++p) {
                    const float xv = row[a][bb + p];   // col w0+p+bb-1
                    // P(x), Horner
                    float P = fmaf(n5, xv, n4);
                    P = fmaf(P, xv, n3);
                    P = fmaf(P, xv, n2);
                    P = fmaf(P, xv, n1);
                    P = fmaf(P, xv, n0);
                    // Q(x) = 1 + |x*(((d3 x + d2) x + d1) x + d0)|
                    float Q = fmaf(d3, xv, d2);
                    Q = fmaf(Q, xv, d1);
                    Q = fmaf(Q, xv, d0);
                    Q *= xv;
                    Q = 1.0f + fabsf(Q);               // abs folds into v_add input modifier
                    acc[p] = fmaf(P, __builtin_amdgcn_rcpf(Q), acc[p]);
                }
            }
        }
    }

    float* op = out + (((size_t)b * F_ + f) * H_ + gy0) * W_ + w0;
    *(float4*)op = make_float4(acc[0], acc[1], acc[2], acc[3]);
}

extern "C" void kernel_launch(void* const* d_in, const int* in_sizes, int n_in,
                              void* d_out, int out_size, void* d_ws, size_t ws_size,
                              hipStream_t stream) {
    const float* x      = (const float*)d_in[0];
    const float* nums   = (const float*)d_in[1];
    const float* denoms = (const float*)d_in[2];
    float* outp = (float*)d_out;
    dim3 grid(B_ * NT_ * F_);   // 512 blocks: (b, tile, f)
    ka_rconv_kernel<<<grid, 256, 0, stream>>>(x, nums, denoms, outp);
}

// Round 3
// 93.091 us; speedup vs baseline: 1.1512x; 1.0043x over previous
//
#include <hip/hip_runtime.h>

#define B_ 4
#define C_ 16
#define H_ 64
#define W_ 64
#define F_ 32

// 1 output pixel per thread: 8192 waves total = 32 waves/CU (max occupancy).
// Block = 256 threads = 4 rows x 64 cols of one (b, f).
__global__ __launch_bounds__(256)
void ka_rconv_kernel(const float* __restrict__ xin,
                     const float* __restrict__ nums,
                     const float* __restrict__ denoms,
                     float* __restrict__ out) {
    const int tid = threadIdx.x;
    const int col = tid & 63;
    const int r   = tid >> 6;

    int bid = blockIdx.x;
    const int f = bid & (F_ - 1);  bid >>= 5;
    const int q = bid & 15;        bid >>= 4;   // row-quad (4 rows each)
    const int b = bid;
    const int gy = q * 4 + r;

    // Clamped neighbor offsets (constant across channels) + validity flags.
    int   offs[3][3];
    bool  ok[3][3];
    #pragma unroll
    for (int a = 0; a < 3; ++a) {
        const int gy2 = gy + a - 1;
        const bool vy = (gy2 >= 0) & (gy2 < H_);
        const int gyc = min(max(gy2, 0), H_ - 1);
        #pragma unroll
        for (int bb = 0; bb < 3; ++bb) {
            const int gx2 = col + bb - 1;
            const bool vx = (gx2 >= 0) & (gx2 < W_);
            const int gxc = min(max(gx2, 0), W_ - 1);
            offs[a][bb] = gyc * W_ + gxc;
            ok[a][bb]   = vy & vx;
        }
    }

    const float* nbase = nums   + f * (C_ * 54);   // uniform -> s_load
    const float* dbase = denoms + f * (C_ * 36);
    const float* xb    = xin + (size_t)b * C_ * H_ * W_;

    float acc = 0.f;

    #pragma unroll 2
    for (int c = 0; c < C_; ++c) {
        const float* xc = xb + c * (H_ * W_);
        float xv[3][3];
        #pragma unroll
        for (int a = 0; a < 3; ++a)
            #pragma unroll
            for (int bb = 0; bb < 3; ++bb) {
                float v = xc[offs[a][bb]];         // always in-bounds (clamped)
                xv[a][bb] = ok[a][bb] ? v : 0.f;   // zero-pad semantics -> cndmask
            }

        const float* np = nbase + c * 54;
        const float* dp = dbase + c * 36;
        #pragma unroll
        for (int a = 0; a < 3; ++a) {
            #pragma unroll
            for (int bb = 0; bb < 3; ++bb) {
                const int t = a * 3 + bb;
                const float xvv = xv[a][bb];
                float P = fmaf(np[t*6+5], xvv, np[t*6+4]);
                P = fmaf(P, xvv, np[t*6+3]);
                P = fmaf(P, xvv, np[t*6+2]);
                P = fmaf(P, xvv, np[t*6+1]);
                P = fmaf(P, xvv, np[t*6+0]);
                float Q = fmaf(dp[t*4+3], xvv, dp[t*4+2]);
                Q = fmaf(Q, xvv, dp[t*4+1]);
                Q = fmaf(Q, xvv, dp[t*4+0]);
                Q *= xvv;
                Q = 1.0f + fabsf(Q);
                acc = fmaf(P, __builtin_amdgcn_rcpf(Q), acc);
            }
        }
    }

    out[(((size_t)b * F_ + f) * H_ + gy) * W_ + col] = acc;
}

extern "C" void kernel_launch(void* const* d_in, const int* in_sizes, int n_in,
                              void* d_out, int out_size, void* d_ws, size_t ws_size,
                              hipStream_t stream) {
    const float* x      = (const float*)d_in[0];
    const float* nums   = (const float*)d_in[1];
    const float* denoms = (const float*)d_in[2];
    float* outp = (float*)d_out;
    dim3 grid(B_ * 16 * F_);   // 2048 blocks: (b, row-quad, f)
    ka_rconv_kernel<<<grid, 256, 0, stream>>>(x, nums, denoms, outp);
}

// Round 4
// 87.802 us; speedup vs baseline: 1.2205x; 1.0602x over previous
//
#include <hip/hip_runtime.h>

#define B_ 4
#define C_ 16
#define H_ 64
#define W_ 64
#define F_ 32

// 2 output rows per thread. Block = 256 threads = 64 cols x 4 row-pairs -> 8 rows.
// Grid = B * 8 * F = 1024 blocks = 4096 waves = 4 waves/SIMD, ILP x2 per wave.
__global__ __launch_bounds__(256)
void ka_rconv_kernel(const float* __restrict__ xin,
                     const float* __restrict__ nums,
                     const float* __restrict__ denoms,
                     float* __restrict__ out) {
    const int tid = threadIdx.x;
    const int col = tid & 63;          // lane = column -> coalesced
    const int rp  = tid >> 6;          // row-pair within block (0..3)

    int bid = blockIdx.x;
    const int f  = bid & 31;  bid >>= 5;
    const int t8 = bid & 7;   bid >>= 3;   // 8-row tile
    const int b  = bid;
    const int gy0 = t8 * 8 + rp * 2;       // first of this thread's 2 rows

    // 12 clamped offsets (rows gy0-1..gy0+2, cols col-1..col+1) + float 0/1 masks.
    // Constant across channels -> computed once, held in VGPRs.
    int   off[4][3];
    float msk[4][3];
    #pragma unroll
    for (int a = 0; a < 4; ++a) {
        const int gy   = gy0 + a - 1;
        const bool vy  = (gy >= 0) && (gy < H_);
        const int gyc  = min(max(gy, 0), H_ - 1);
        #pragma unroll
        for (int j = 0; j < 3; ++j) {
            const int gx  = col + j - 1;
            const bool vx = (gx >= 0) && (gx < W_);
            const int gxc = min(max(gx, 0), W_ - 1);
            off[a][j] = gyc * W_ + gxc;
            msk[a][j] = (vy && vx) ? 1.0f : 0.0f;   // zero-pad: padded tap contributes n0/1
        }
    }

    const float* nbase = nums   + f * (C_ * 54);   // uniform -> scalar loads
    const float* dbase = denoms + f * (C_ * 36);
    const float* xb    = xin + (size_t)b * C_ * (H_ * W_);

    float acc0 = 0.f, acc1 = 0.f;

    for (int c = 0; c < C_; ++c) {
        const float* xc = xb + c * (H_ * W_);
        float xv[4][3];
        #pragma unroll
        for (int a = 0; a < 4; ++a)
            #pragma unroll
            for (int j = 0; j < 3; ++j)
                xv[a][j] = xc[off[a][j]] * msk[a][j];   // clamped load, mask-mul to zero

        const float* np = nbase + c * 54;
        const float* dp = dbase + c * 36;
        #pragma unroll
        for (int a = 0; a < 3; ++a) {
            #pragma unroll
            for (int j = 0; j < 3; ++j) {
                const int t = a * 3 + j;
                const float n0 = np[t*6+0], n1 = np[t*6+1], n2 = np[t*6+2];
                const float n3 = np[t*6+3], n4 = np[t*6+4], n5 = np[t*6+5];
                const float d0 = dp[t*4+0], d1 = dp[t*4+1], d2 = dp[t*4+2], d3 = dp[t*4+3];

                const float x0 = xv[a][j];       // pixel row gy0
                const float x1 = xv[a + 1][j];   // pixel row gy0+1

                float P0 = fmaf(n5, x0, n4);
                float P1 = fmaf(n5, x1, n4);
                P0 = fmaf(P0, x0, n3);  P1 = fmaf(P1, x1, n3);
                P0 = fmaf(P0, x0, n2);  P1 = fmaf(P1, x1, n2);
                P0 = fmaf(P0, x0, n1);  P1 = fmaf(P1, x1, n1);
                P0 = fmaf(P0, x0, n0);  P1 = fmaf(P1, x1, n0);

                float Q0 = fmaf(d3, x0, d2);
                float Q1 = fmaf(d3, x1, d2);
                Q0 = fmaf(Q0, x0, d1);  Q1 = fmaf(Q1, x1, d1);
                Q0 = fmaf(Q0, x0, d0);  Q1 = fmaf(Q1, x1, d0);
                Q0 *= x0;               Q1 *= x1;
                Q0 = 1.0f + fabsf(Q0);  Q1 = 1.0f + fabsf(Q1);

                acc0 = fmaf(P0, __builtin_amdgcn_rcpf(Q0), acc0);
                acc1 = fmaf(P1, __builtin_amdgcn_rcpf(Q1), acc1);
            }
        }
    }

    float* op = out + (((size_t)b * F_ + f) * H_ + gy0) * W_ + col;
    op[0]  = acc0;
    op[W_] = acc1;
}

extern "C" void kernel_launch(void* const* d_in, const int* in_sizes, int n_in,
                              void* d_out, int out_size, void* d_ws, size_t ws_size,
                              hipStream_t stream) {
    const float* x      = (const float*)d_in[0];
    const float* nums   = (const float*)d_in[1];
    const float* denoms = (const float*)d_in[2];
    float* outp = (float*)d_out;
    dim3 grid(B_ * 8 * F_);   // 1024 blocks: (b, 8-row tile, f)
    ka_rconv_kernel<<<grid, 256, 0, stream>>>(x, nums, denoms, outp);
}